// Round 1
// baseline (567.854 us; speedup 1.0000x reference)
//
#include <hip/hip_runtime.h>
#include <hip/hip_bf16.h>
#include <math.h>

#define NR 50      // rho grid points per dim
#define NP 200     // phi grid points per dim
#define NM 400     // mirrored width (2*NP)
#define SCADD 1e-12

// ws layout (in doubles)
#define OFF_KY   0        // 50x50 Cholesky of Ky
#define OFF_KX   2500     // 50x50 Cholesky of Kx
#define OFF_T    5000     // Ky^{-1} P   (50x50)
#define OFF_M    7500     // model matrix M[iy][ix] (50x50)
#define OFF_AT   10000    // Atab[a][iy] 200x50
#define OFF_BT   20000    // Btab[b][ix] 200x50
#define OFF_T2   30000    // T2[iy][b]   50x200
#define OFF_EPS  40000    // eps[a][b]   200x200
#define OFF_EX   80000    // ex[a][b]    200x400
#define OFF_EY   160000   // ey[a][b]    200x400
#define OFF_PART 240000   // per-block partials
#define NBLK_C2  313      // ceil(80000/256)

// ---------------- Kernel A: build Ky,Kx, Cholesky, solve for model ----------
__global__ void solve_kernel(const float* __restrict__ params,
                             const float* __restrict__ x_rho,
                             const float* __restrict__ y_rho,
                             double* __restrict__ ws) {
    double* Ky = ws + OFF_KY;
    double* Kx = ws + OFF_KX;
    double* T  = ws + OFF_T;
    double* M  = ws + OFF_M;
    __shared__ double scol[NR * 64];   // per-thread solve column

    const int tid = threadIdx.x;       // blockDim = 64
    const double Lr = (double)y_rho[NR-1] - (double)y_rho[0];
    const double sigma = 0.8 * Lr / (double)(NR - 1);
    const double inv2s2 = 1.0 / (2.0 * sigma * sigma);

    // build kernel matrices (fp64)
    for (int idx = tid; idx < NR*NR; idx += blockDim.x) {
        int i = idx / NR, j = idx % NR;
        double dy = (double)y_rho[i] - (double)y_rho[j];
        Ky[idx] = exp(-dy*dy*inv2s2);
        double dx = (double)x_rho[i] - (double)x_rho[j];
        Kx[idx] = exp(-dx*dx*inv2s2);
    }
    __syncthreads();

    // in-place lower Cholesky of both
    for (int m = 0; m < 2; ++m) {
        double* A = m ? Kx : Ky;
        for (int j = 0; j < NR; ++j) {
            if (tid == 0) {
                double s = A[j*NR+j];
                for (int k = 0; k < j; ++k) s -= A[j*NR+k]*A[j*NR+k];
                A[j*NR+j] = sqrt(s);
            }
            __syncthreads();
            double dj = A[j*NR+j];
            for (int i = j+1+tid; i < NR; i += blockDim.x) {
                double s = A[i*NR+j];
                for (int k = 0; k < j; ++k) s -= A[i*NR+k]*A[j*NR+k];
                A[i*NR+j] = s / dj;
            }
            __syncthreads();
        }
    }

    // T = Ky^{-1} P : one RHS column (ix) per thread
    if (tid < NR) {
        const int ix = tid;
        // forward  L y = b
        for (int i = 0; i < NR; ++i) {
            double s = (double)params[i*NR + ix];
            for (int k = 0; k < i; ++k) s -= Ky[i*NR+k]*scol[k*64+tid];
            scol[i*64+tid] = s / Ky[i*NR+i];
        }
        // backward L^T x = y
        for (int i = NR-1; i >= 0; --i) {
            double s = scol[i*64+tid];
            for (int k = i+1; k < NR; ++k) s -= Ky[k*NR+i]*scol[k*64+tid];
            scol[i*64+tid] = s / Ky[i*NR+i];
        }
        for (int i = 0; i < NR; ++i) T[i*NR+ix] = scol[i*64+tid];
    }
    __syncthreads();

    // M = T Kx^{-1}  (Kx symmetric): solve Kx z = T[iy,:]^T, one row per thread
    if (tid < NR) {
        const int iy = tid;
        for (int i = 0; i < NR; ++i) {
            double s = T[iy*NR + i];
            for (int k = 0; k < i; ++k) s -= Kx[i*NR+k]*scol[k*64+tid];
            scol[i*64+tid] = s / Kx[i*NR+i];
        }
        for (int i = NR-1; i >= 0; --i) {
            double s = scol[i*64+tid];
            for (int k = i+1; k < NR; ++k) s -= Kx[k*NR+i]*scol[k*64+tid];
            scol[i*64+tid] = s / Kx[i*NR+i];
        }
        for (int ix = 0; ix < NR; ++ix) M[iy*NR+ix] = scol[ix*64+tid];
    }
}

// ---------------- Kernel B0: evaluation tables ------------------------------
__global__ void tables_kernel(const float* __restrict__ x_rho,
                              const float* __restrict__ y_rho,
                              const float* __restrict__ x_phi,
                              const float* __restrict__ y_phi,
                              double* __restrict__ ws) {
    double* Atab = ws + OFF_AT;
    double* Btab = ws + OFF_BT;
    const int idx = blockIdx.x * blockDim.x + threadIdx.x;
    const double Lr = (double)y_rho[NR-1] - (double)y_rho[0];
    const double sigma = 0.8 * Lr / (double)(NR - 1);
    const double inv2s2 = 1.0 / (2.0 * sigma * sigma);
    if (idx < NP*NR) {
        int a = idx / NR, iy = idx % NR;
        double d = (double)y_phi[a] - (double)y_rho[iy];
        Atab[idx] = exp(-d*d*inv2s2);
    } else if (idx < 2*NP*NR) {
        int t = idx - NP*NR;
        int b = t / NR, ix = t % NR;
        double d = (double)x_phi[b] - (double)x_rho[ix];
        Btab[t] = exp(-d*d*inv2s2);
    }
}

// ---------------- Kernel B1: T2 = M * Btab^T --------------------------------
__global__ void gemm1_kernel(double* __restrict__ ws) {
    const double* M    = ws + OFF_M;
    const double* Btab = ws + OFF_BT;
    double* T2 = ws + OFF_T2;
    const int idx = blockIdx.x * blockDim.x + threadIdx.x;
    if (idx >= NR*NP) return;
    const int iy = idx / NP, b = idx % NP;
    double s = 0.0;
    for (int ix = 0; ix < NR; ++ix) s += M[iy*NR+ix] * Btab[b*NR+ix];
    T2[iy*NP + b] = s;
}

// ---------------- Kernel B2: phi = Atab * T2, eps = 0.5(tanh(.1 phi)+1) -----
__global__ void gemm2_kernel(double* __restrict__ ws) {
    const double* Atab = ws + OFF_AT;
    const double* T2   = ws + OFF_T2;
    double* eps = ws + OFF_EPS;
    const int idx = blockIdx.x * blockDim.x + threadIdx.x;
    if (idx >= NP*NP) return;
    const int a = idx / NP, b = idx % NP;
    double s = 0.0;
    for (int iy = 0; iy < NR; ++iy) s += Atab[a*NR+iy] * T2[iy*NP+b];
    eps[idx] = 0.5 * (tanh(0.1 * s) + 1.0);
}

// mirror accessor over the (NP x NM) conceptual field
__device__ __forceinline__ double Emap(const double* eps, int a, int b) {
    int bb = (b < NP) ? b : (2*NP - 1 - b);
    return eps[a*NP + bb];
}

// ---------------- Kernel C1: first derivatives ex, ey -----------------------
__global__ void grad1_kernel(const float* __restrict__ x_phi,
                             double* __restrict__ ws) {
    const double* eps = ws + OFF_EPS;
    double* ex = ws + OFF_EX;
    double* ey = ws + OFF_EY;
    const int idx = blockIdx.x * blockDim.x + threadIdx.x;
    if (idx >= NP*NM) return;
    const int a = idx / NM, b = idx % NM;
    const double g = ((double)x_phi[NP-1] - (double)x_phi[0]) / (double)(NP - 1);

    double vx;
    if (a == 0)            vx = (Emap(eps,1,b)   - Emap(eps,0,b))   / g;
    else if (a == NP-1)    vx = (Emap(eps,a,b)   - Emap(eps,a-1,b)) / g;
    else                   vx = (Emap(eps,a+1,b) - Emap(eps,a-1,b)) / (2.0*g);
    ex[idx] = vx + SCADD;

    double vy;
    if (b == 0)            vy = (Emap(eps,a,1)   - Emap(eps,a,0))   / g;
    else if (b == NM-1)    vy = (Emap(eps,a,b)   - Emap(eps,a,b-1)) / g;
    else                   vy = (Emap(eps,a,b+1) - Emap(eps,a,b-1)) / (2.0*g);
    ey[idx] = vy + SCADD;
}

__device__ __forceinline__ double gradA(const double* f, int a, int b, double g) {
    if (a == 0)         return (f[1*NM+b]     - f[0*NM+b])     / g;
    if (a == NP-1)      return (f[a*NM+b]     - f[(a-1)*NM+b]) / g;
    return (f[(a+1)*NM+b] - f[(a-1)*NM+b]) / (2.0*g);
}
__device__ __forceinline__ double gradB(const double* f, int a, int b, double g) {
    if (b == 0)         return (f[a*NM+1]   - f[a*NM+0])   / g;
    if (b == NM-1)      return (f[a*NM+b]   - f[a*NM+b-1]) / g;
    return (f[a*NM+b+1] - f[a*NM+b-1]) / (2.0*g);
}

// ---------------- Kernel C2: curvature penalty, per-block partial sums ------
__global__ void penalty_kernel(const float* __restrict__ x_phi,
                               double* __restrict__ ws) {
    const double* eps = ws + OFF_EPS;
    const double* ex  = ws + OFF_EX;
    const double* ey  = ws + OFF_EY;
    double* part = ws + OFF_PART;
    __shared__ double sdata[256];

    const int idx = blockIdx.x * blockDim.x + threadIdx.x;
    const double g = ((double)x_phi[NP-1] - (double)x_phi[0]) / (double)(NP - 1);
    const double pi_d = M_PI / 1.1;   // pi / (1.1 * MIN_FEATURE_SIZE)

    double local = 0.0;
    if (idx < NP*NM) {
        const int a = idx / NM, b = idx % NM;
        const double exv = ex[idx];
        const double eyv = ey[idx];
        const double exx = gradA(ex, a, b, g);
        const double exy = gradB(ex, a, b, g);
        const double eyy = gradB(ey, a, b, g);
        double epsv = sqrt(exv*exv + eyv*eyv);
        const double epsv_min = 1e-32 / 6.0;
        if (epsv < epsv_min) epsv = epsv_min;
        const double kk = (exv*exv*eyy - 2.0*exv*eyv*exy + eyv*eyv*exx)
                          / (epsv*epsv*epsv);
        const double cc = fabs(kk * atan(epsv / Emap(eps, a, b))) - pi_d;
        double v = fmax(cc, 0.0) * g * g;   // fmax(NaN,0)=0 == nansum semantics
        if (!isnan(v)) local = v;
    }
    sdata[threadIdx.x] = local;
    __syncthreads();
    for (int s = 128; s > 0; s >>= 1) {
        if (threadIdx.x < s) sdata[threadIdx.x] += sdata[threadIdx.x + s];
        __syncthreads();
    }
    if (threadIdx.x == 0) part[blockIdx.x] = sdata[0];
}

// ---------------- Kernel C3: deterministic final sum ------------------------
__global__ void finalize_kernel(double* __restrict__ ws, float* __restrict__ out) {
    const double* part = ws + OFF_PART;
    double s = 0.0;
    for (int i = 0; i < NBLK_C2; ++i) s += part[i];
    out[0] = (float)s;
}

extern "C" void kernel_launch(void* const* d_in, const int* in_sizes, int n_in,
                              void* d_out, int out_size, void* d_ws, size_t ws_size,
                              hipStream_t stream) {
    const float* params = (const float*)d_in[0];
    const float* x_rho  = (const float*)d_in[1];
    const float* y_rho  = (const float*)d_in[2];
    const float* x_phi  = (const float*)d_in[3];
    const float* y_phi  = (const float*)d_in[4];
    double* ws = (double*)d_ws;
    float* out = (float*)d_out;

    solve_kernel<<<1, 64, 0, stream>>>(params, x_rho, y_rho, ws);
    tables_kernel<<<(2*NP*NR + 255)/256, 256, 0, stream>>>(x_rho, y_rho, x_phi, y_phi, ws);
    gemm1_kernel<<<(NR*NP + 255)/256, 256, 0, stream>>>(ws);
    gemm2_kernel<<<(NP*NP + 255)/256, 256, 0, stream>>>(ws);
    grad1_kernel<<<(NP*NM + 255)/256, 256, 0, stream>>>(x_phi, ws);
    penalty_kernel<<<NBLK_C2, 256, 0, stream>>>(x_phi, ws);
    finalize_kernel<<<1, 1, 0, stream>>>(ws, out);
}

// Round 2
// 198.997 us; speedup vs baseline: 2.8536x; 2.8536x over previous
//
#include <hip/hip_runtime.h>
#include <hip/hip_bf16.h>
#include <math.h>

#define NR 50      // rho grid points per dim
#define NRP 51     // padded LDS row stride
#define NP 200     // phi grid points per dim
#define NM 400     // mirrored width (2*NP)
#define SCADD 1e-12

// ws layout (in doubles) — unchanged from R0 (ws_size already sufficient)
#define OFF_M    7500     // model matrix M[iy][ix] (50x50)
#define OFF_AT   10000    // Atab[a][iy] 200x50
#define OFF_BT   20000    // Btab[b][ix] 200x50
#define OFF_T2   30000    // T2[iy][b]   50x200
#define OFF_EPS  40000    // eps[a][b]   200x200
#define OFF_EX   80000    // ex[a][b]    200x400
#define OFF_EY   160000   // ey[a][b]    200x400
#define OFF_PART 240000   // per-block partials
#define NBLK_C2  313      // ceil(80000/256)

// ---------------- Kernel A: build Ky,Kx, Cholesky, solve for model ----------
// All solve state in LDS; both Choleskys run concurrently (one per wave).
__global__ __launch_bounds__(128) void solve_kernel(
        const float* __restrict__ params,
        const float* __restrict__ x_rho,
        const float* __restrict__ y_rho,
        double* __restrict__ ws) {
    __shared__ double A0[NR * NRP];   // Ky -> Cholesky; later reused as Z workspace
    __shared__ double A1[NR * NRP];   // Kx -> Cholesky
    __shared__ double S[NR * NR];     // P copy -> in-place solve -> T
    __shared__ double xr[NR], yr[NR];

    const int tid = threadIdx.x;      // blockDim = 128 (2 waves)
    if (tid < NR) { xr[tid] = (double)x_rho[tid]; yr[tid] = (double)y_rho[tid]; }
    // coalesced copy of params into S (same linear layout: S[i*NR+ix])
    for (int idx = tid; idx < NR * NR; idx += 128)
        S[idx] = (double)params[idx];
    __syncthreads();

    const double Lr = yr[NR - 1] - yr[0];
    const double sigma = 0.8 * Lr / (double)(NR - 1);
    const double inv2s2 = 1.0 / (2.0 * sigma * sigma);

    // build both kernel matrices in LDS (fp64)
    for (int idx = tid; idx < NR * NR; idx += 128) {
        int i = idx / NR, j = idx % NR;
        double dy = yr[i] - yr[j];
        A0[i * NRP + j] = exp(-dy * dy * inv2s2);
        double dx = xr[i] - xr[j];
        A1[i * NRP + j] = exp(-dx * dx * inv2s2);
    }
    __syncthreads();

    // fused lower Cholesky: wave0 -> A0 (Ky), wave1 -> A1 (Kx)
    {
        double* A = (tid < 64) ? A0 : A1;
        const int t = tid & 63;                 // lane within wave
        for (int j = 0; j < NR; ++j) {
            const int i = j + t;                // rows j..NR-1 across lanes
            double s = 0.0;
            if (i < NR) {
                s = A[i * NRP + j];
                for (int k = 0; k < j; ++k)
                    s -= A[i * NRP + k] * A[j * NRP + k];
            }
            // lane 0 (i==j) holds the diagonal dot; broadcast within the wave
            double sdiag = __shfl(s, 0, 64);
            double d = sqrt(sdiag);
            if (i < NR)
                A[i * NRP + j] = (t == 0) ? d : (s / d);
            __syncthreads();                    // column j final before next column
        }
    }

    // Phase 1: T = Ky^{-1} P, in place in S. One RHS column (ix=tid) per thread.
    if (tid < NR) {
        // forward  L y = p  (in place)
        for (int i = 0; i < NR; ++i) {
            double s = S[i * NR + tid];
            for (int k = 0; k < i; ++k) s -= A0[i * NRP + k] * S[k * NR + tid];
            S[i * NR + tid] = s / A0[i * NRP + i];
        }
        // backward L^T x = y (in place)
        for (int i = NR - 1; i >= 0; --i) {
            double s = S[i * NR + tid];
            for (int k = i + 1; k < NR; ++k) s -= A0[k * NRP + i] * S[k * NR + tid];
            S[i * NR + tid] = s / A0[i * NRP + i];
        }
    }
    __syncthreads();   // S now holds T[r][c]; A0 free for reuse

    // Phase 2: M = T Kx^{-1}; thread tid solves Kx z = T[iy=tid, :]^T using A1.
    // Workspace Z reuses A0's LDS.
    if (tid < NR) {
        double* Z = A0;
        for (int i = 0; i < NR; ++i) {
            double s = S[tid * NR + i];          // RHS: T[tid][i]
            for (int k = 0; k < i; ++k) s -= A1[i * NRP + k] * Z[k * NRP + tid];
            Z[i * NRP + tid] = s / A1[i * NRP + i];
        }
        for (int i = NR - 1; i >= 0; --i) {
            double s = Z[i * NRP + tid];
            for (int k = i + 1; k < NR; ++k) s -= A1[k * NRP + i] * Z[k * NRP + tid];
            Z[i * NRP + tid] = s / A1[i * NRP + i];
        }
        double* M = ws + OFF_M;
        for (int ix = 0; ix < NR; ++ix)
            M[tid * NR + ix] = Z[ix * NRP + tid];
    }
}

// ---------------- Kernel B0: evaluation tables ------------------------------
__global__ void tables_kernel(const float* __restrict__ x_rho,
                              const float* __restrict__ y_rho,
                              const float* __restrict__ x_phi,
                              const float* __restrict__ y_phi,
                              double* __restrict__ ws) {
    double* Atab = ws + OFF_AT;
    double* Btab = ws + OFF_BT;
    const int idx = blockIdx.x * blockDim.x + threadIdx.x;
    const double Lr = (double)y_rho[NR-1] - (double)y_rho[0];
    const double sigma = 0.8 * Lr / (double)(NR - 1);
    const double inv2s2 = 1.0 / (2.0 * sigma * sigma);
    if (idx < NP*NR) {
        int a = idx / NR, iy = idx % NR;
        double d = (double)y_phi[a] - (double)y_rho[iy];
        Atab[idx] = exp(-d*d*inv2s2);
    } else if (idx < 2*NP*NR) {
        int t = idx - NP*NR;
        int b = t / NR, ix = t % NR;
        double d = (double)x_phi[b] - (double)x_rho[ix];
        Btab[t] = exp(-d*d*inv2s2);
    }
}

// ---------------- Kernel B1: T2 = M * Btab^T --------------------------------
__global__ void gemm1_kernel(double* __restrict__ ws) {
    const double* M    = ws + OFF_M;
    const double* Btab = ws + OFF_BT;
    double* T2 = ws + OFF_T2;
    const int idx = blockIdx.x * blockDim.x + threadIdx.x;
    if (idx >= NR*NP) return;
    const int iy = idx / NP, b = idx % NP;
    double s = 0.0;
    for (int ix = 0; ix < NR; ++ix) s += M[iy*NR+ix] * Btab[b*NR+ix];
    T2[iy*NP + b] = s;
}

// ---------------- Kernel B2: phi = Atab * T2, eps = 0.5(tanh(.1 phi)+1) -----
__global__ void gemm2_kernel(double* __restrict__ ws) {
    const double* Atab = ws + OFF_AT;
    const double* T2   = ws + OFF_T2;
    double* eps = ws + OFF_EPS;
    const int idx = blockIdx.x * blockDim.x + threadIdx.x;
    if (idx >= NP*NP) return;
    const int a = idx / NP, b = idx % NP;
    double s = 0.0;
    for (int iy = 0; iy < NR; ++iy) s += Atab[a*NR+iy] * T2[iy*NP+b];
    eps[idx] = 0.5 * (tanh(0.1 * s) + 1.0);
}

// mirror accessor over the (NP x NM) conceptual field
__device__ __forceinline__ double Emap(const double* eps, int a, int b) {
    int bb = (b < NP) ? b : (2*NP - 1 - b);
    return eps[a*NP + bb];
}

// ---------------- Kernel C1: first derivatives ex, ey -----------------------
__global__ void grad1_kernel(const float* __restrict__ x_phi,
                             double* __restrict__ ws) {
    const double* eps = ws + OFF_EPS;
    double* ex = ws + OFF_EX;
    double* ey = ws + OFF_EY;
    const int idx = blockIdx.x * blockDim.x + threadIdx.x;
    if (idx >= NP*NM) return;
    const int a = idx / NM, b = idx % NM;
    const double g = ((double)x_phi[NP-1] - (double)x_phi[0]) / (double)(NP - 1);

    double vx;
    if (a == 0)            vx = (Emap(eps,1,b)   - Emap(eps,0,b))   / g;
    else if (a == NP-1)    vx = (Emap(eps,a,b)   - Emap(eps,a-1,b)) / g;
    else                   vx = (Emap(eps,a+1,b) - Emap(eps,a-1,b)) / (2.0*g);
    ex[idx] = vx + SCADD;

    double vy;
    if (b == 0)            vy = (Emap(eps,a,1)   - Emap(eps,a,0))   / g;
    else if (b == NM-1)    vy = (Emap(eps,a,b)   - Emap(eps,a,b-1)) / g;
    else                   vy = (Emap(eps,a,b+1) - Emap(eps,a,b-1)) / (2.0*g);
    ey[idx] = vy + SCADD;
}

__device__ __forceinline__ double gradA(const double* f, int a, int b, double g) {
    if (a == 0)         return (f[1*NM+b]     - f[0*NM+b])     / g;
    if (a == NP-1)      return (f[a*NM+b]     - f[(a-1)*NM+b]) / g;
    return (f[(a+1)*NM+b] - f[(a-1)*NM+b]) / (2.0*g);
}
__device__ __forceinline__ double gradB(const double* f, int a, int b, double g) {
    if (b == 0)         return (f[a*NM+1]   - f[a*NM+0])   / g;
    if (b == NM-1)      return (f[a*NM+b]   - f[a*NM+b-1]) / g;
    return (f[a*NM+b+1] - f[a*NM+b-1]) / (2.0*g);
}

// ---------------- Kernel C2: curvature penalty, per-block partial sums ------
__global__ void penalty_kernel(const float* __restrict__ x_phi,
                               double* __restrict__ ws) {
    const double* eps = ws + OFF_EPS;
    const double* ex  = ws + OFF_EX;
    const double* ey  = ws + OFF_EY;
    double* part = ws + OFF_PART;
    __shared__ double sdata[256];

    const int idx = blockIdx.x * blockDim.x + threadIdx.x;
    const double g = ((double)x_phi[NP-1] - (double)x_phi[0]) / (double)(NP - 1);
    const double pi_d = M_PI / 1.1;   // pi / (1.1 * MIN_FEATURE_SIZE)

    double local = 0.0;
    if (idx < NP*NM) {
        const int a = idx / NM, b = idx % NM;
        const double exv = ex[idx];
        const double eyv = ey[idx];
        const double exx = gradA(ex, a, b, g);
        const double exy = gradB(ex, a, b, g);
        const double eyy = gradB(ey, a, b, g);
        double epsv = sqrt(exv*exv + eyv*eyv);
        const double epsv_min = 1e-32 / 6.0;
        if (epsv < epsv_min) epsv = epsv_min;
        const double kk = (exv*exv*eyy - 2.0*exv*eyv*exy + eyv*eyv*exx)
                          / (epsv*epsv*epsv);
        const double cc = fabs(kk * atan(epsv / Emap(eps, a, b))) - pi_d;
        double v = fmax(cc, 0.0) * g * g;
        if (!isnan(v)) local = v;
    }
    sdata[threadIdx.x] = local;
    __syncthreads();
    for (int s = 128; s > 0; s >>= 1) {
        if (threadIdx.x < s) sdata[threadIdx.x] += sdata[threadIdx.x + s];
        __syncthreads();
    }
    if (threadIdx.x == 0) part[blockIdx.x] = sdata[0];
}

// ---------------- Kernel C3: deterministic final sum ------------------------
__global__ void finalize_kernel(double* __restrict__ ws, float* __restrict__ out) {
    const double* part = ws + OFF_PART;
    double s = 0.0;
    for (int i = 0; i < NBLK_C2; ++i) s += part[i];
    out[0] = (float)s;
}

extern "C" void kernel_launch(void* const* d_in, const int* in_sizes, int n_in,
                              void* d_out, int out_size, void* d_ws, size_t ws_size,
                              hipStream_t stream) {
    const float* params = (const float*)d_in[0];
    const float* x_rho  = (const float*)d_in[1];
    const float* y_rho  = (const float*)d_in[2];
    const float* x_phi  = (const float*)d_in[3];
    const float* y_phi  = (const float*)d_in[4];
    double* ws = (double*)d_ws;
    float* out = (float*)d_out;

    solve_kernel<<<1, 128, 0, stream>>>(params, x_rho, y_rho, ws);
    tables_kernel<<<(2*NP*NR + 255)/256, 256, 0, stream>>>(x_rho, y_rho, x_phi, y_phi, ws);
    gemm1_kernel<<<(NR*NP + 255)/256, 256, 0, stream>>>(ws);
    gemm2_kernel<<<(NP*NP + 255)/256, 256, 0, stream>>>(ws);
    grad1_kernel<<<(NP*NM + 255)/256, 256, 0, stream>>>(x_phi, ws);
    penalty_kernel<<<NBLK_C2, 256, 0, stream>>>(x_phi, ws);
    finalize_kernel<<<1, 1, 0, stream>>>(ws, out);
}